// Round 7
// baseline (1923.784 us; speedup 1.0000x reference)
//
#include <hip/hip_runtime.h>

// Sinkhorn EMD, B=8, N=2048, eps=0.005, 50 iters.
// R7 = R6 (IC-coherent atomics, no flushes — validated 2.35x) + candidate-
// list sparsification: eps=0.005 makes the Gibbs kernel so peaked that only
// columns with x >= L - 64 (log2) can ever matter (excluded ones are
// < 2^-34 relative even after 24 passes of drift). Lists built during
// dense passes {10,11,34,35,58,59,82,83} (rebuild kills drift risk),
// sparse passes gather ~100-200 cols instead of 2048. CAP overflow ->
// per-row dense fallback. Lists are block-private -> live in LDS (~125KB,
// 1 block/CU unchanged). dis uses f-side lists.
// Numerics validated R3-R6: online LSE passes 0-5, fixed-shift M =
// own previous log-sum, clamp +100, absmax 0.0 at every round.

#define BB 8
#define NN 2048
#define NPASS 100
#define ONLINE_PASSES 6
#define RPW 8
#define GRID_BLOCKS 256
#define BLOCKS_PER_BATCH 32
#define TPB 1024
#define CAP 192
#define MARGIN 64.0f

constexpr float EPSV = 0.005f;
constexpr float KS   = EPSV * 0.69314718055994531f; // eps*ln2
constexpr float INVK = 1.0f / KS;
constexpr float C1V  = -EPSV * 7.6246189861593985f; // eps*log(1/2048)
constexpr float KQ4  = KS * 0.25f;        // |g|^2/K = KQ4 * |G|^2
constexpr float TWOI = 2.0f * INVK;       // G = TWOI * g

__device__ __forceinline__ float fexp2(float x) { return __builtin_amdgcn_exp2f(x); }
__device__ __forceinline__ float flog2(float x) { return __builtin_amdgcn_logf(x); }

__device__ __forceinline__ float cohLoad(const float* p) {
    return __hip_atomic_load(p, __ATOMIC_RELAXED, __HIP_MEMORY_SCOPE_AGENT);
}
__device__ __forceinline__ void cohStore(float* p, float v) {
    __hip_atomic_store(p, v, __ATOMIC_RELAXED, __HIP_MEMORY_SCOPE_AGENT);
}

__device__ __forceinline__ void barrier_sync(int* ctr, int target) {
    __syncthreads();
    if (threadIdx.x == 0) {
        __hip_atomic_fetch_add(ctr, 1, __ATOMIC_RELAXED, __HIP_MEMORY_SCOPE_AGENT);
        while (__hip_atomic_load(ctr, __ATOMIC_RELAXED, __HIP_MEMORY_SCOPE_AGENT) < target) {
            __builtin_amdgcn_s_sleep(2);
        }
    }
    __syncthreads();
}

__global__ void __launch_bounds__(TPB, 4) emd_persist(
    const float* __restrict__ preds, const float* __restrict__ gts,
    float* __restrict__ fpot, float* __restrict__ gpot,
    float* __restrict__ partials, int* __restrict__ bctr, int* __restrict__ gctr,
    float* __restrict__ out)
{
    __shared__ float4 sjall[2 * NN];     // {Gx,Gy,Gz,-|g|^2/K}; 0=gts 1=preds
    __shared__ float  sa[NN];            // active-side potential column pot/K
    __shared__ float  sPrevL[2][64];     // [side][row-in-block] last log-sum
    __shared__ float  smS[64][2];        // [row][half] partial s
    __shared__ float  smM[64][2];        // online-path partial m
    __shared__ float  wred[16];
    __shared__ unsigned short slist[2][64][CAP];  // candidate columns
    __shared__ unsigned int   scnt[2][64];        // candidate counts

    const int blk  = blockIdx.x;
    const int b    = blk >> 5;
    const int rb   = blk & 31;
    const int wave = threadIdx.x >> 6;
    const int lane = threadIdx.x & 63;
    const int grp  = wave & 7;                 // row group (8 rows)
    const int half = wave >> 3;                // column half
    const int row0 = rb * 64 + grp * RPW;
    const int cb   = half << 10;

    const float* pb  = preds + (size_t)b * NN * 3;
    const float* gbp = gts   + (size_t)b * NN * 3;
    float* fb = fpot + (size_t)b * NN;
    float* gb = gpot + (size_t)b * NN;
    int*   bar = bctr + b * 32;

    for (int t = threadIdx.x; t < NN; t += TPB) {
        float gx = gbp[3*t], gy = gbp[3*t+1], gz = gbp[3*t+2];
        float Gx = gx*TWOI, Gy = gy*TWOI, Gz = gz*TWOI;
        sjall[t] = make_float4(Gx, Gy, Gz, -KQ4*(Gx*Gx+Gy*Gy+Gz*Gz));
        float qx = pb[3*t], qy = pb[3*t+1], qz = pb[3*t+2];
        float Qx = qx*TWOI, Qy = qy*TWOI, Qz = qz*TWOI;
        sjall[NN+t] = make_float4(Qx, Qy, Qz, -KQ4*(Qx*Qx+Qy*Qy+Qz*Qz));
    }

#pragma unroll 1
    for (int pass = 0; pass < NPASS; ++pass) {
        const int odd = pass & 1;                  // side index
        const float* rpts = odd ? gbp : pb;
        const float* pin  = odd ? fb  : gb;
        float*       pout = odd ? gb  : fb;
        const int    sjo  = odd ? NN  : 0;
        const bool is_build  = (pass >= 10) && (((pass - 10) % 24) < 2);
        const bool is_sparse = (pass >= 12) && !is_build;

        for (int t = threadIdx.x; t < NN; t += TPB)
            sa[t] = cohLoad(&pin[t]) * INVK;
        if (is_build && threadIdx.x < 64) scnt[odd][threadIdx.x] = 0;

        float px[RPW], py[RPW], pz[RPW], pn[RPW], M[RPW], s[RPW];
#pragma unroll
        for (int r = 0; r < RPW; ++r) {
            int i = row0 + r;
            px[r] = rpts[3*i]; py[r] = rpts[3*i+1]; pz[r] = rpts[3*i+2];
            pn[r] = px[r]*px[r] + py[r]*py[r] + pz[r]*pz[r];
            s[r]  = 0.f;
        }
        if (pass >= ONLINE_PASSES) {
#pragma unroll
            for (int r = 0; r < RPW; ++r)
                M[r] = sPrevL[odd][grp*RPW + r];
        }
        __syncthreads();

        if (pass < ONLINE_PASSES) {
            float m[RPW];
#pragma unroll
            for (int r = 0; r < RPW; ++r) m[r] = -1e30f;
#pragma unroll 4
            for (int c = 0; c < 16; ++c) {
                float4 d = sjall[sjo + cb + c*64 + lane];
                float aw = d.w + sa[cb + c*64 + lane];
#pragma unroll
                for (int r = 0; r < RPW; ++r) {
                    float x  = fmaf(px[r], d.x, fmaf(py[r], d.y, fmaf(pz[r], d.z, aw)));
                    float mn = fmaxf(m[r], x);
                    s[r] = fmaf(s[r], fexp2(m[r]-mn), fexp2(x-mn));
                    m[r] = mn;
                }
            }
#pragma unroll
            for (int r = 0; r < RPW; ++r) {
                float mm = m[r], ss = s[r];
                for (int off = 1; off < 64; off <<= 1) {
                    float mo = __shfl_xor(mm, off, 64);
                    float so = __shfl_xor(ss, off, 64);
                    float mn = fmaxf(mm, mo);
                    ss = fmaf(ss, fexp2(mm-mn), so * fexp2(mo-mn));
                    mm = mn;
                }
                m[r] = mm; s[r] = ss;
            }
            if (lane == 0) {
#pragma unroll
                for (int r = 0; r < RPW; ++r) {
                    smM[grp*RPW + r][half] = m[r];
                    smS[grp*RPW + r][half] = s[r];
                }
            }
            __syncthreads();
            if (half == 1 && lane == 0) {
#pragma unroll
                for (int r = 0; r < RPW; ++r) {
                    float mo = smM[grp*RPW + r][0], so = smS[grp*RPW + r][0];
                    float mn = fmaxf(m[r], mo);
                    float st = fmaf(s[r], fexp2(m[r]-mn), so * fexp2(mo-mn));
                    float L  = mn + flog2(fmaxf(st, 1e-37f));
                    sPrevL[odd][grp*RPW + r] = L;
                    cohStore(&pout[row0+r], C1V + pn[r] - KS * L);
                }
            }
            barrier_sync(bar, BLOCKS_PER_BATCH * (pass + 1));
            continue;
        }

        if (is_build) {
            // dense + compact candidates (r-outer for per-row ballots)
#pragma unroll 1
            for (int r = 0; r < RPW; ++r) {
                const int rowloc = grp*RPW + r;
                const float thr = M[r] - MARGIN;
                float ss = 0.f;
                for (int c = 0; c < 16; ++c) {
                    int j = cb + c*64 + lane;
                    float4 d = sjall[sjo + j];
                    float aw = d.w + sa[j];
                    float x = fmaf(px[r], d.x, fmaf(py[r], d.y, fmaf(pz[r], d.z, aw)));
                    ss += fexp2(fminf(x - M[r], 100.f));
                    bool pred = (x >= thr);
                    unsigned long long mask = __ballot((int)pred);
                    int npop = __popcll(mask);
                    unsigned int base = 0;
                    if (lane == 0 && npop)
                        base = atomicAdd(&scnt[odd][rowloc], (unsigned)npop);
                    base = (unsigned)__shfl((int)base, 0, 64);
                    if (pred) {
                        unsigned int pos = base + __popcll(mask & ((1ull << lane) - 1ull));
                        if (pos < CAP) slist[odd][rowloc][pos] = (unsigned short)j;
                    }
                }
                s[r] = ss;
            }
        } else if (!is_sparse) {
            // plain dense fixed-shift (passes 6..9)
#pragma unroll 4
            for (int c = 0; c < 16; ++c) {
                float4 d = sjall[sjo + cb + c*64 + lane];
                float aw = d.w + sa[cb + c*64 + lane];
#pragma unroll
                for (int r = 0; r < RPW; ++r) {
                    float x = fmaf(px[r], d.x, fmaf(py[r], d.y, fmaf(pz[r], d.z, aw)));
                    s[r] += fexp2(fminf(x - M[r], 100.f));
                }
            }
        } else {
            // sparse gather over candidate list; dense fallback on overflow
#pragma unroll 1
            for (int r = 0; r < RPW; ++r) {
                const int rowloc = grp*RPW + r;
                const unsigned int cnt = scnt[odd][rowloc];
                float ss = 0.f;
                if (cnt <= CAP) {
                    for (unsigned int k = (half << 6) + lane; k < cnt; k += 128) {
                        int j = slist[odd][rowloc][k];
                        float4 d = sjall[sjo + j];
                        float aw = d.w + sa[j];
                        float x = fmaf(px[r], d.x, fmaf(py[r], d.y, fmaf(pz[r], d.z, aw)));
                        ss += fexp2(fminf(x - M[r], 100.f));
                    }
                } else {
                    for (int c = 0; c < 16; ++c) {
                        int j = cb + c*64 + lane;
                        float4 d = sjall[sjo + j];
                        float aw = d.w + sa[j];
                        float x = fmaf(px[r], d.x, fmaf(py[r], d.y, fmaf(pz[r], d.z, aw)));
                        ss += fexp2(fminf(x - M[r], 100.f));
                    }
                }
                s[r] = ss;
            }
        }

        // shared tail for all fixed-shift variants
#pragma unroll
        for (int r = 0; r < RPW; ++r) {
            float ss = s[r];
            for (int off = 1; off < 64; off <<= 1) ss += __shfl_xor(ss, off, 64);
            s[r] = ss;
        }
        if (lane == 0) {
#pragma unroll
            for (int r = 0; r < RPW; ++r) smS[grp*RPW + r][half] = s[r];
        }
        __syncthreads();
        if (half == 1 && lane == 0) {
#pragma unroll
            for (int r = 0; r < RPW; ++r) {
                float st = s[r] + smS[grp*RPW + r][0];
                float L  = M[r] + flog2(fmaxf(st, 1e-37f));
                sPrevL[odd][grp*RPW + r] = L;
                cohStore(&pout[row0+r], C1V + pn[r] - KS * L);
            }
        }
        barrier_sync(bar, BLOCKS_PER_BATCH * (pass + 1));
    }

    // ---- dis: sum P*C over cols = gts (side 0), f-side candidate lists ----
    for (int t = threadIdx.x; t < NN; t += TPB)
        sa[t] = cohLoad(&gb[t]) * INVK;

    float px[RPW], py[RPW], pz[RPW], pn[RPW], bb2[RPW], acc[RPW];
#pragma unroll
    for (int r = 0; r < RPW; ++r) {
        int i = row0 + r;
        px[r] = pb[3*i]; py[r] = pb[3*i+1]; pz[r] = pb[3*i+2];
        pn[r] = px[r]*px[r] + py[r]*py[r] + pz[r]*pz[r];
        bb2[r] = C1V * INVK - sPrevL[0][grp*RPW + r];
        acc[r] = 0.f;
    }
    __syncthreads();
#pragma unroll 1
    for (int r = 0; r < RPW; ++r) {
        const int rowloc = grp*RPW + r;
        const unsigned int cnt = scnt[0][rowloc];
        float aa = 0.f;
        if (cnt <= CAP) {
            for (unsigned int k = (half << 6) + lane; k < cnt; k += 128) {
                int j = slist[0][rowloc][k];
                float4 d = sjall[j];
                float aw = d.w + sa[j];
                float gn = -KS * d.w;
                float dot = fmaf(px[r], d.x, fmaf(py[r], d.y, pz[r]*d.z));
                float y   = dot + aw + bb2[r];
                float e   = fexp2(fminf(y, 80.f));
                aa = fmaf(e, fmaf(-KS, dot, pn[r] + gn), aa);
            }
        } else {
            for (int c = 0; c < 16; ++c) {
                int j = cb + c*64 + lane;
                float4 d = sjall[j];
                float aw = d.w + sa[j];
                float gn = -KS * d.w;
                float dot = fmaf(px[r], d.x, fmaf(py[r], d.y, pz[r]*d.z));
                float y   = dot + aw + bb2[r];
                float e   = fexp2(fminf(y, 80.f));
                aa = fmaf(e, fmaf(-KS, dot, pn[r] + gn), aa);
            }
        }
        acc[r] = aa;
    }
    float tot = 0.f;
#pragma unroll
    for (int r = 0; r < RPW; ++r) tot += acc[r];
    for (int off = 1; off < 64; off <<= 1) tot += __shfl_xor(tot, off, 64);
    if (lane == 0) wred[wave] = tot;
    __syncthreads();
    if (threadIdx.x == 0) {
        float v = 0.f;
        for (int w = 0; w < 16; ++w) v += wred[w];
        cohStore(&partials[blk], v);
    }

    barrier_sync(gctr, GRID_BLOCKS);

    if (blk == 0) {
        float v = (threadIdx.x < GRID_BLOCKS) ? cohLoad(&partials[threadIdx.x]) : 0.f;
        for (int off = 1; off < 64; off <<= 1) v += __shfl_xor(v, off, 64);
        if (lane == 0) wred[wave] = v;
        __syncthreads();
        if (threadIdx.x == 0) {
            float t2 = 0.f;
            for (int w = 0; w < 16; ++w) t2 += wred[w];
            out[0] = t2 * (1.0f / BB);
        }
    }
}

extern "C" void kernel_launch(void* const* d_in, const int* in_sizes, int n_in,
                              void* d_out, int out_size, void* d_ws, size_t ws_size,
                              hipStream_t stream) {
    const float* preds = (const float*)d_in[0];
    const float* gts   = (const float*)d_in[1];
    float* fp       = (float*)d_ws;
    float* gp       = fp + BB * NN;
    float* partials = gp + BB * NN;
    int*   bctr     = (int*)(partials + GRID_BLOCKS);
    int*   gctr     = bctr + BB * 32;
    float* out      = (float*)d_out;

    size_t zbytes = (size_t)(2 * BB * NN + GRID_BLOCKS) * sizeof(float)
                  + (size_t)(BB * 32 + 32) * sizeof(int);
    hipMemsetAsync(d_ws, 0, zbytes, stream);

    emd_persist<<<dim3(GRID_BLOCKS), dim3(TPB), 0, stream>>>(
        preds, gts, fp, gp, partials, bctr, gctr, out);
}

// Round 8
// 929.516 us; speedup vs baseline: 2.0697x; 2.0697x over previous
//
#include <hip/hip_runtime.h>

// Sinkhorn EMD, B=8, N=2048, eps=0.005, 50 iters.
// R8 = R7 with the scratch-spill fixed: every r-loop touching per-row
// state (px/py/pz/pn/M/s/acc) is FULLY UNROLLED so the arrays live in
// VGPRs (R7's `#pragma unroll 1` + runtime index demoted them to scratch
// -> 1.16GB WRITE_SIZE -> HBM-bound). Structure otherwise identical:
// IC-coherent atomics, no flushes (R6, 2.35x); candidate-list sparsity
// with MARGIN=64, rebuilds every 24 passes (R7, absmax 0.0).

#define BB 8
#define NN 2048
#define NPASS 100
#define ONLINE_PASSES 6
#define RPW 8
#define GRID_BLOCKS 256
#define BLOCKS_PER_BATCH 32
#define TPB 1024
#define CAP 192
#define MARGIN 64.0f

constexpr float EPSV = 0.005f;
constexpr float KS   = EPSV * 0.69314718055994531f; // eps*ln2
constexpr float INVK = 1.0f / KS;
constexpr float C1V  = -EPSV * 7.6246189861593985f; // eps*log(1/2048)
constexpr float KQ4  = KS * 0.25f;
constexpr float TWOI = 2.0f * INVK;

__device__ __forceinline__ float fexp2(float x) { return __builtin_amdgcn_exp2f(x); }
__device__ __forceinline__ float flog2(float x) { return __builtin_amdgcn_logf(x); }

__device__ __forceinline__ float cohLoad(const float* p) {
    return __hip_atomic_load(p, __ATOMIC_RELAXED, __HIP_MEMORY_SCOPE_AGENT);
}
__device__ __forceinline__ void cohStore(float* p, float v) {
    __hip_atomic_store(p, v, __ATOMIC_RELAXED, __HIP_MEMORY_SCOPE_AGENT);
}

__device__ __forceinline__ void barrier_sync(int* ctr, int target) {
    __syncthreads();
    if (threadIdx.x == 0) {
        __hip_atomic_fetch_add(ctr, 1, __ATOMIC_RELAXED, __HIP_MEMORY_SCOPE_AGENT);
        while (__hip_atomic_load(ctr, __ATOMIC_RELAXED, __HIP_MEMORY_SCOPE_AGENT) < target) {
            __builtin_amdgcn_s_sleep(2);
        }
    }
    __syncthreads();
}

__global__ void __launch_bounds__(TPB, 4) emd_persist(
    const float* __restrict__ preds, const float* __restrict__ gts,
    float* __restrict__ fpot, float* __restrict__ gpot,
    float* __restrict__ partials, int* __restrict__ bctr, int* __restrict__ gctr,
    float* __restrict__ out)
{
    __shared__ float4 sjall[2 * NN];
    __shared__ float  sa[NN];
    __shared__ float  sPrevL[2][64];
    __shared__ float  smS[64][2];
    __shared__ float  smM[64][2];
    __shared__ float  wred[16];
    __shared__ unsigned short slist[2][64][CAP];
    __shared__ unsigned int   scnt[2][64];

    const int blk  = blockIdx.x;
    const int b    = blk >> 5;
    const int rb   = blk & 31;
    const int wave = threadIdx.x >> 6;
    const int lane = threadIdx.x & 63;
    const int grp  = wave & 7;
    const int half = wave >> 3;
    const int row0 = rb * 64 + grp * RPW;
    const int cb   = half << 10;

    const float* pb  = preds + (size_t)b * NN * 3;
    const float* gbp = gts   + (size_t)b * NN * 3;
    float* fb = fpot + (size_t)b * NN;
    float* gb = gpot + (size_t)b * NN;
    int*   bar = bctr + b * 32;

    for (int t = threadIdx.x; t < NN; t += TPB) {
        float gx = gbp[3*t], gy = gbp[3*t+1], gz = gbp[3*t+2];
        float Gx = gx*TWOI, Gy = gy*TWOI, Gz = gz*TWOI;
        sjall[t] = make_float4(Gx, Gy, Gz, -KQ4*(Gx*Gx+Gy*Gy+Gz*Gz));
        float qx = pb[3*t], qy = pb[3*t+1], qz = pb[3*t+2];
        float Qx = qx*TWOI, Qy = qy*TWOI, Qz = qz*TWOI;
        sjall[NN+t] = make_float4(Qx, Qy, Qz, -KQ4*(Qx*Qx+Qy*Qy+Qz*Qz));
    }

#pragma unroll 1
    for (int pass = 0; pass < NPASS; ++pass) {
        const int odd = pass & 1;
        const float* rpts = odd ? gbp : pb;
        const float* pin  = odd ? fb  : gb;
        float*       pout = odd ? gb  : fb;
        const int    sjo  = odd ? NN  : 0;
        const bool is_build  = (pass >= 10) && (((pass - 10) % 24) < 2);
        const bool is_sparse = (pass >= 12) && !is_build;

        for (int t = threadIdx.x; t < NN; t += TPB)
            sa[t] = cohLoad(&pin[t]) * INVK;
        if (is_build && threadIdx.x < 64) scnt[odd][threadIdx.x] = 0;

        float px[RPW], py[RPW], pz[RPW], pn[RPW], M[RPW], s[RPW];
#pragma unroll
        for (int r = 0; r < RPW; ++r) {
            int i = row0 + r;
            px[r] = rpts[3*i]; py[r] = rpts[3*i+1]; pz[r] = rpts[3*i+2];
            pn[r] = px[r]*px[r] + py[r]*py[r] + pz[r]*pz[r];
            s[r]  = 0.f;
        }
        if (pass >= ONLINE_PASSES) {
#pragma unroll
            for (int r = 0; r < RPW; ++r)
                M[r] = sPrevL[odd][grp*RPW + r];
        }
        __syncthreads();

        if (pass < ONLINE_PASSES) {
            float m[RPW];
#pragma unroll
            for (int r = 0; r < RPW; ++r) m[r] = -1e30f;
#pragma unroll 4
            for (int c = 0; c < 16; ++c) {
                float4 d = sjall[sjo + cb + c*64 + lane];
                float aw = d.w + sa[cb + c*64 + lane];
#pragma unroll
                for (int r = 0; r < RPW; ++r) {
                    float x  = fmaf(px[r], d.x, fmaf(py[r], d.y, fmaf(pz[r], d.z, aw)));
                    float mn = fmaxf(m[r], x);
                    s[r] = fmaf(s[r], fexp2(m[r]-mn), fexp2(x-mn));
                    m[r] = mn;
                }
            }
#pragma unroll
            for (int r = 0; r < RPW; ++r) {
                float mm = m[r], ss = s[r];
                for (int off = 1; off < 64; off <<= 1) {
                    float mo = __shfl_xor(mm, off, 64);
                    float so = __shfl_xor(ss, off, 64);
                    float mn = fmaxf(mm, mo);
                    ss = fmaf(ss, fexp2(mm-mn), so * fexp2(mo-mn));
                    mm = mn;
                }
                m[r] = mm; s[r] = ss;
            }
            if (lane == 0) {
#pragma unroll
                for (int r = 0; r < RPW; ++r) {
                    smM[grp*RPW + r][half] = m[r];
                    smS[grp*RPW + r][half] = s[r];
                }
            }
            __syncthreads();
            if (half == 1 && lane == 0) {
#pragma unroll
                for (int r = 0; r < RPW; ++r) {
                    float mo = smM[grp*RPW + r][0], so = smS[grp*RPW + r][0];
                    float mn = fmaxf(m[r], mo);
                    float st = fmaf(s[r], fexp2(m[r]-mn), so * fexp2(mo-mn));
                    float L  = mn + flog2(fmaxf(st, 1e-37f));
                    sPrevL[odd][grp*RPW + r] = L;
                    cohStore(&pout[row0+r], C1V + pn[r] - KS * L);
                }
            }
            barrier_sync(bar, BLOCKS_PER_BATCH * (pass + 1));
            continue;
        }

        if (is_build) {
            // dense + candidate compaction; r fully unrolled (regs!)
#pragma unroll
            for (int r = 0; r < RPW; ++r) {
                const int rowloc = grp*RPW + r;
                const float thr = M[r] - MARGIN;
                float ss = 0.f;
#pragma unroll 1
                for (int c = 0; c < 16; ++c) {
                    int j = cb + c*64 + lane;
                    float4 d = sjall[sjo + j];
                    float aw = d.w + sa[j];
                    float x = fmaf(px[r], d.x, fmaf(py[r], d.y, fmaf(pz[r], d.z, aw)));
                    ss += fexp2(fminf(x - M[r], 100.f));
                    bool pred = (x >= thr);
                    unsigned long long mask = __ballot((int)pred);
                    int npop = __popcll(mask);
                    unsigned int base = 0;
                    if (lane == 0 && npop)
                        base = atomicAdd(&scnt[odd][rowloc], (unsigned)npop);
                    base = (unsigned)__shfl((int)base, 0, 64);
                    if (pred) {
                        unsigned int pos = base + __popcll(mask & ((1ull << lane) - 1ull));
                        if (pos < CAP) slist[odd][rowloc][pos] = (unsigned short)j;
                    }
                }
                s[r] = ss;
            }
        } else if (!is_sparse) {
            // plain dense fixed-shift (passes 6..9)
#pragma unroll 4
            for (int c = 0; c < 16; ++c) {
                float4 d = sjall[sjo + cb + c*64 + lane];
                float aw = d.w + sa[cb + c*64 + lane];
#pragma unroll
                for (int r = 0; r < RPW; ++r) {
                    float x = fmaf(px[r], d.x, fmaf(py[r], d.y, fmaf(pz[r], d.z, aw)));
                    s[r] += fexp2(fminf(x - M[r], 100.f));
                }
            }
        } else {
            // sparse gather; r fully unrolled, per-row dynamic k-loop
#pragma unroll
            for (int r = 0; r < RPW; ++r) {
                const int rowloc = grp*RPW + r;
                const unsigned int cnt = scnt[odd][rowloc];
                float ss = 0.f;
                if (cnt <= CAP) {
#pragma unroll 1
                    for (unsigned int k = (half << 6) + lane; k < cnt; k += 128) {
                        int j = slist[odd][rowloc][k];
                        float4 d = sjall[sjo + j];
                        float aw = d.w + sa[j];
                        float x = fmaf(px[r], d.x, fmaf(py[r], d.y, fmaf(pz[r], d.z, aw)));
                        ss += fexp2(fminf(x - M[r], 100.f));
                    }
                } else {
#pragma unroll 1
                    for (int c = 0; c < 16; ++c) {
                        int j = cb + c*64 + lane;
                        float4 d = sjall[sjo + j];
                        float aw = d.w + sa[j];
                        float x = fmaf(px[r], d.x, fmaf(py[r], d.y, fmaf(pz[r], d.z, aw)));
                        ss += fexp2(fminf(x - M[r], 100.f));
                    }
                }
                s[r] = ss;
            }
        }

        // shared tail for fixed-shift variants
#pragma unroll
        for (int r = 0; r < RPW; ++r) {
            float ss = s[r];
            for (int off = 1; off < 64; off <<= 1) ss += __shfl_xor(ss, off, 64);
            s[r] = ss;
        }
        if (lane == 0) {
#pragma unroll
            for (int r = 0; r < RPW; ++r) smS[grp*RPW + r][half] = s[r];
        }
        __syncthreads();
        if (half == 1 && lane == 0) {
#pragma unroll
            for (int r = 0; r < RPW; ++r) {
                float st = s[r] + smS[grp*RPW + r][0];
                float L  = M[r] + flog2(fmaxf(st, 1e-37f));
                sPrevL[odd][grp*RPW + r] = L;
                cohStore(&pout[row0+r], C1V + pn[r] - KS * L);
            }
        }
        barrier_sync(bar, BLOCKS_PER_BATCH * (pass + 1));
    }

    // ---- dis: sum P*C over cols = gts (side 0), f-side lists ----
    for (int t = threadIdx.x; t < NN; t += TPB)
        sa[t] = cohLoad(&gb[t]) * INVK;

    float px[RPW], py[RPW], pz[RPW], pn[RPW], bb2[RPW], acc[RPW];
#pragma unroll
    for (int r = 0; r < RPW; ++r) {
        int i = row0 + r;
        px[r] = pb[3*i]; py[r] = pb[3*i+1]; pz[r] = pb[3*i+2];
        pn[r] = px[r]*px[r] + py[r]*py[r] + pz[r]*pz[r];
        bb2[r] = C1V * INVK - sPrevL[0][grp*RPW + r];
        acc[r] = 0.f;
    }
    __syncthreads();
#pragma unroll
    for (int r = 0; r < RPW; ++r) {
        const int rowloc = grp*RPW + r;
        const unsigned int cnt = scnt[0][rowloc];
        float aa = 0.f;
        if (cnt <= CAP) {
#pragma unroll 1
            for (unsigned int k = (half << 6) + lane; k < cnt; k += 128) {
                int j = slist[0][rowloc][k];
                float4 d = sjall[j];
                float aw = d.w + sa[j];
                float gn = -KS * d.w;
                float dot = fmaf(px[r], d.x, fmaf(py[r], d.y, pz[r]*d.z));
                float y   = dot + aw + bb2[r];
                float e   = fexp2(fminf(y, 80.f));
                aa = fmaf(e, fmaf(-KS, dot, pn[r] + gn), aa);
            }
        } else {
#pragma unroll 1
            for (int c = 0; c < 16; ++c) {
                int j = cb + c*64 + lane;
                float4 d = sjall[j];
                float aw = d.w + sa[j];
                float gn = -KS * d.w;
                float dot = fmaf(px[r], d.x, fmaf(py[r], d.y, pz[r]*d.z));
                float y   = dot + aw + bb2[r];
                float e   = fexp2(fminf(y, 80.f));
                aa = fmaf(e, fmaf(-KS, dot, pn[r] + gn), aa);
            }
        }
        acc[r] = aa;
    }
    float tot = 0.f;
#pragma unroll
    for (int r = 0; r < RPW; ++r) tot += acc[r];
    for (int off = 1; off < 64; off <<= 1) tot += __shfl_xor(tot, off, 64);
    if (lane == 0) wred[wave] = tot;
    __syncthreads();
    if (threadIdx.x == 0) {
        float v = 0.f;
        for (int w = 0; w < 16; ++w) v += wred[w];
        cohStore(&partials[blk], v);
    }

    barrier_sync(gctr, GRID_BLOCKS);

    if (blk == 0) {
        float v = (threadIdx.x < GRID_BLOCKS) ? cohLoad(&partials[threadIdx.x]) : 0.f;
        for (int off = 1; off < 64; off <<= 1) v += __shfl_xor(v, off, 64);
        if (lane == 0) wred[wave] = v;
        __syncthreads();
        if (threadIdx.x == 0) {
            float t2 = 0.f;
            for (int w = 0; w < 16; ++w) t2 += wred[w];
            out[0] = t2 * (1.0f / BB);
        }
    }
}

extern "C" void kernel_launch(void* const* d_in, const int* in_sizes, int n_in,
                              void* d_out, int out_size, void* d_ws, size_t ws_size,
                              hipStream_t stream) {
    const float* preds = (const float*)d_in[0];
    const float* gts   = (const float*)d_in[1];
    float* fp       = (float*)d_ws;
    float* gp       = fp + BB * NN;
    float* partials = gp + BB * NN;
    int*   bctr     = (int*)(partials + GRID_BLOCKS);
    int*   gctr     = bctr + BB * 32;
    float* out      = (float*)d_out;

    size_t zbytes = (size_t)(2 * BB * NN + GRID_BLOCKS) * sizeof(float)
                  + (size_t)(BB * 32 + 32) * sizeof(int);
    hipMemsetAsync(d_ws, 0, zbytes, stream);

    emd_persist<<<dim3(GRID_BLOCKS), dim3(TPB), 0, stream>>>(
        preds, gts, fp, gp, partials, bctr, gctr, out);
}

// Round 9
// 897.211 us; speedup vs baseline: 2.1442x; 1.0360x over previous
//
#include <hip/hip_runtime.h>

// Sinkhorn EMD, B=8, N=2048, eps=0.005, 50 iters.
// R9 = R8 + overflow-straggler fix: MARGIN 64->48 (still 2^-48 truncation,
// 24 log2 drift budget per <=23-pass rebuild gap), CAP 192->256 (LDS
// ~142KB, still 1 block/CU). Builds at {6,7,+24k}; passes 8+ all sparse.
// Validated invariants: IC-coherent atomics / no flushes (R6); fully
// unrolled r-loops = no scratch spill (R8); online LSE passes 0-5 +
// fixed-shift M = own previous log-sum (R3+, absmax 0.0 every round).

#define BB 8
#define NN 2048
#define NPASS 100
#define ONLINE_PASSES 6
#define RPW 8
#define GRID_BLOCKS 256
#define BLOCKS_PER_BATCH 32
#define TPB 1024
#define CAP 256
#define MARGIN 48.0f

constexpr float EPSV = 0.005f;
constexpr float KS   = EPSV * 0.69314718055994531f; // eps*ln2
constexpr float INVK = 1.0f / KS;
constexpr float C1V  = -EPSV * 7.6246189861593985f; // eps*log(1/2048)
constexpr float KQ4  = KS * 0.25f;
constexpr float TWOI = 2.0f * INVK;

__device__ __forceinline__ float fexp2(float x) { return __builtin_amdgcn_exp2f(x); }
__device__ __forceinline__ float flog2(float x) { return __builtin_amdgcn_logf(x); }

__device__ __forceinline__ float cohLoad(const float* p) {
    return __hip_atomic_load(p, __ATOMIC_RELAXED, __HIP_MEMORY_SCOPE_AGENT);
}
__device__ __forceinline__ void cohStore(float* p, float v) {
    __hip_atomic_store(p, v, __ATOMIC_RELAXED, __HIP_MEMORY_SCOPE_AGENT);
}

__device__ __forceinline__ void barrier_sync(int* ctr, int target) {
    __syncthreads();
    if (threadIdx.x == 0) {
        __hip_atomic_fetch_add(ctr, 1, __ATOMIC_RELAXED, __HIP_MEMORY_SCOPE_AGENT);
        while (__hip_atomic_load(ctr, __ATOMIC_RELAXED, __HIP_MEMORY_SCOPE_AGENT) < target) {
            __builtin_amdgcn_s_sleep(2);
        }
    }
    __syncthreads();
}

__global__ void __launch_bounds__(TPB, 4) emd_persist(
    const float* __restrict__ preds, const float* __restrict__ gts,
    float* __restrict__ fpot, float* __restrict__ gpot,
    float* __restrict__ partials, int* __restrict__ bctr, int* __restrict__ gctr,
    float* __restrict__ out)
{
    __shared__ float4 sjall[2 * NN];
    __shared__ float  sa[NN];
    __shared__ float  sPrevL[2][64];
    __shared__ float  smS[64][2];
    __shared__ float  smM[64][2];
    __shared__ float  wred[16];
    __shared__ unsigned short slist[2][64][CAP];
    __shared__ unsigned int   scnt[2][64];

    const int blk  = blockIdx.x;
    const int b    = blk >> 5;
    const int rb   = blk & 31;
    const int wave = threadIdx.x >> 6;
    const int lane = threadIdx.x & 63;
    const int grp  = wave & 7;
    const int half = wave >> 3;
    const int row0 = rb * 64 + grp * RPW;
    const int cb   = half << 10;

    const float* pb  = preds + (size_t)b * NN * 3;
    const float* gbp = gts   + (size_t)b * NN * 3;
    float* fb = fpot + (size_t)b * NN;
    float* gb = gpot + (size_t)b * NN;
    int*   bar = bctr + b * 32;

    for (int t = threadIdx.x; t < NN; t += TPB) {
        float gx = gbp[3*t], gy = gbp[3*t+1], gz = gbp[3*t+2];
        float Gx = gx*TWOI, Gy = gy*TWOI, Gz = gz*TWOI;
        sjall[t] = make_float4(Gx, Gy, Gz, -KQ4*(Gx*Gx+Gy*Gy+Gz*Gz));
        float qx = pb[3*t], qy = pb[3*t+1], qz = pb[3*t+2];
        float Qx = qx*TWOI, Qy = qy*TWOI, Qz = qz*TWOI;
        sjall[NN+t] = make_float4(Qx, Qy, Qz, -KQ4*(Qx*Qx+Qy*Qy+Qz*Qz));
    }

#pragma unroll 1
    for (int pass = 0; pass < NPASS; ++pass) {
        const int odd = pass & 1;
        const float* rpts = odd ? gbp : pb;
        const float* pin  = odd ? fb  : gb;
        float*       pout = odd ? gb  : fb;
        const int    sjo  = odd ? NN  : 0;
        const bool is_build  = (pass >= ONLINE_PASSES) &&
                               (((pass - ONLINE_PASSES) % 24) < 2);
        const bool is_sparse = (pass >= ONLINE_PASSES) && !is_build;

        for (int t = threadIdx.x; t < NN; t += TPB)
            sa[t] = cohLoad(&pin[t]) * INVK;
        if (is_build && threadIdx.x < 64) scnt[odd][threadIdx.x] = 0;

        float px[RPW], py[RPW], pz[RPW], pn[RPW], M[RPW], s[RPW];
#pragma unroll
        for (int r = 0; r < RPW; ++r) {
            int i = row0 + r;
            px[r] = rpts[3*i]; py[r] = rpts[3*i+1]; pz[r] = rpts[3*i+2];
            pn[r] = px[r]*px[r] + py[r]*py[r] + pz[r]*pz[r];
            s[r]  = 0.f;
        }
        if (pass >= ONLINE_PASSES) {
#pragma unroll
            for (int r = 0; r < RPW; ++r)
                M[r] = sPrevL[odd][grp*RPW + r];
        }
        __syncthreads();

        if (pass < ONLINE_PASSES) {
            float m[RPW];
#pragma unroll
            for (int r = 0; r < RPW; ++r) m[r] = -1e30f;
#pragma unroll 4
            for (int c = 0; c < 16; ++c) {
                float4 d = sjall[sjo + cb + c*64 + lane];
                float aw = d.w + sa[cb + c*64 + lane];
#pragma unroll
                for (int r = 0; r < RPW; ++r) {
                    float x  = fmaf(px[r], d.x, fmaf(py[r], d.y, fmaf(pz[r], d.z, aw)));
                    float mn = fmaxf(m[r], x);
                    s[r] = fmaf(s[r], fexp2(m[r]-mn), fexp2(x-mn));
                    m[r] = mn;
                }
            }
#pragma unroll
            for (int r = 0; r < RPW; ++r) {
                float mm = m[r], ss = s[r];
                for (int off = 1; off < 64; off <<= 1) {
                    float mo = __shfl_xor(mm, off, 64);
                    float so = __shfl_xor(ss, off, 64);
                    float mn = fmaxf(mm, mo);
                    ss = fmaf(ss, fexp2(mm-mn), so * fexp2(mo-mn));
                    mm = mn;
                }
                m[r] = mm; s[r] = ss;
            }
            if (lane == 0) {
#pragma unroll
                for (int r = 0; r < RPW; ++r) {
                    smM[grp*RPW + r][half] = m[r];
                    smS[grp*RPW + r][half] = s[r];
                }
            }
            __syncthreads();
            if (half == 1 && lane == 0) {
#pragma unroll
                for (int r = 0; r < RPW; ++r) {
                    float mo = smM[grp*RPW + r][0], so = smS[grp*RPW + r][0];
                    float mn = fmaxf(m[r], mo);
                    float st = fmaf(s[r], fexp2(m[r]-mn), so * fexp2(mo-mn));
                    float L  = mn + flog2(fmaxf(st, 1e-37f));
                    sPrevL[odd][grp*RPW + r] = L;
                    cohStore(&pout[row0+r], C1V + pn[r] - KS * L);
                }
            }
            barrier_sync(bar, BLOCKS_PER_BATCH * (pass + 1));
            continue;
        }

        if (is_build) {
            // dense + candidate compaction; r fully unrolled (VGPRs)
#pragma unroll
            for (int r = 0; r < RPW; ++r) {
                const int rowloc = grp*RPW + r;
                const float thr = M[r] - MARGIN;
                float ss = 0.f;
#pragma unroll 1
                for (int c = 0; c < 16; ++c) {
                    int j = cb + c*64 + lane;
                    float4 d = sjall[sjo + j];
                    float aw = d.w + sa[j];
                    float x = fmaf(px[r], d.x, fmaf(py[r], d.y, fmaf(pz[r], d.z, aw)));
                    ss += fexp2(fminf(x - M[r], 100.f));
                    bool pred = (x >= thr);
                    unsigned long long mask = __ballot((int)pred);
                    int npop = __popcll(mask);
                    unsigned int base = 0;
                    if (lane == 0 && npop)
                        base = atomicAdd(&scnt[odd][rowloc], (unsigned)npop);
                    base = (unsigned)__shfl((int)base, 0, 64);
                    if (pred) {
                        unsigned int pos = base + __popcll(mask & ((1ull << lane) - 1ull));
                        if (pos < CAP) slist[odd][rowloc][pos] = (unsigned short)j;
                    }
                }
                s[r] = ss;
            }
        } else {
            // sparse gather; r fully unrolled; rare dense fallback
#pragma unroll
            for (int r = 0; r < RPW; ++r) {
                const int rowloc = grp*RPW + r;
                const unsigned int cnt = scnt[odd][rowloc];
                float ss = 0.f;
                if (cnt <= CAP) {
#pragma unroll 1
                    for (unsigned int k = (half << 6) + lane; k < cnt; k += 128) {
                        int j = slist[odd][rowloc][k];
                        float4 d = sjall[sjo + j];
                        float aw = d.w + sa[j];
                        float x = fmaf(px[r], d.x, fmaf(py[r], d.y, fmaf(pz[r], d.z, aw)));
                        ss += fexp2(fminf(x - M[r], 100.f));
                    }
                } else {
#pragma unroll 1
                    for (int c = 0; c < 16; ++c) {
                        int j = cb + c*64 + lane;
                        float4 d = sjall[sjo + j];
                        float aw = d.w + sa[j];
                        float x = fmaf(px[r], d.x, fmaf(py[r], d.y, fmaf(pz[r], d.z, aw)));
                        ss += fexp2(fminf(x - M[r], 100.f));
                    }
                }
                s[r] = ss;
            }
        }

        // shared tail for fixed-shift variants
#pragma unroll
        for (int r = 0; r < RPW; ++r) {
            float ss = s[r];
            for (int off = 1; off < 64; off <<= 1) ss += __shfl_xor(ss, off, 64);
            s[r] = ss;
        }
        if (lane == 0) {
#pragma unroll
            for (int r = 0; r < RPW; ++r) smS[grp*RPW + r][half] = s[r];
        }
        __syncthreads();
        if (half == 1 && lane == 0) {
#pragma unroll
            for (int r = 0; r < RPW; ++r) {
                float st = s[r] + smS[grp*RPW + r][0];
                float L  = M[r] + flog2(fmaxf(st, 1e-37f));
                sPrevL[odd][grp*RPW + r] = L;
                cohStore(&pout[row0+r], C1V + pn[r] - KS * L);
            }
        }
        barrier_sync(bar, BLOCKS_PER_BATCH * (pass + 1));
    }

    // ---- dis: sum P*C over cols = gts (side 0), f-side lists ----
    for (int t = threadIdx.x; t < NN; t += TPB)
        sa[t] = cohLoad(&gb[t]) * INVK;

    float px[RPW], py[RPW], pz[RPW], pn[RPW], bb2[RPW], acc[RPW];
#pragma unroll
    for (int r = 0; r < RPW; ++r) {
        int i = row0 + r;
        px[r] = pb[3*i]; py[r] = pb[3*i+1]; pz[r] = pb[3*i+2];
        pn[r] = px[r]*px[r] + py[r]*py[r] + pz[r]*pz[r];
        bb2[r] = C1V * INVK - sPrevL[0][grp*RPW + r];
        acc[r] = 0.f;
    }
    __syncthreads();
#pragma unroll
    for (int r = 0; r < RPW; ++r) {
        const int rowloc = grp*RPW + r;
        const unsigned int cnt = scnt[0][rowloc];
        float aa = 0.f;
        if (cnt <= CAP) {
#pragma unroll 1
            for (unsigned int k = (half << 6) + lane; k < cnt; k += 128) {
                int j = slist[0][rowloc][k];
                float4 d = sjall[j];
                float aw = d.w + sa[j];
                float gn = -KS * d.w;
                float dot = fmaf(px[r], d.x, fmaf(py[r], d.y, pz[r]*d.z));
                float y   = dot + aw + bb2[r];
                float e   = fexp2(fminf(y, 80.f));
                aa = fmaf(e, fmaf(-KS, dot, pn[r] + gn), aa);
            }
        } else {
#pragma unroll 1
            for (int c = 0; c < 16; ++c) {
                int j = cb + c*64 + lane;
                float4 d = sjall[j];
                float aw = d.w + sa[j];
                float gn = -KS * d.w;
                float dot = fmaf(px[r], d.x, fmaf(py[r], d.y, pz[r]*d.z));
                float y   = dot + aw + bb2[r];
                float e   = fexp2(fminf(y, 80.f));
                aa = fmaf(e, fmaf(-KS, dot, pn[r] + gn), aa);
            }
        }
        acc[r] = aa;
    }
    float tot = 0.f;
#pragma unroll
    for (int r = 0; r < RPW; ++r) tot += acc[r];
    for (int off = 1; off < 64; off <<= 1) tot += __shfl_xor(tot, off, 64);
    if (lane == 0) wred[wave] = tot;
    __syncthreads();
    if (threadIdx.x == 0) {
        float v = 0.f;
        for (int w = 0; w < 16; ++w) v += wred[w];
        cohStore(&partials[blk], v);
    }

    barrier_sync(gctr, GRID_BLOCKS);

    if (blk == 0) {
        float v = (threadIdx.x < GRID_BLOCKS) ? cohLoad(&partials[threadIdx.x]) : 0.f;
        for (int off = 1; off < 64; off <<= 1) v += __shfl_xor(v, off, 64);
        if (lane == 0) wred[wave] = v;
        __syncthreads();
        if (threadIdx.x == 0) {
            float t2 = 0.f;
            for (int w = 0; w < 16; ++w) t2 += wred[w];
            out[0] = t2 * (1.0f / BB);
        }
    }
}

extern "C" void kernel_launch(void* const* d_in, const int* in_sizes, int n_in,
                              void* d_out, int out_size, void* d_ws, size_t ws_size,
                              hipStream_t stream) {
    const float* preds = (const float*)d_in[0];
    const float* gts   = (const float*)d_in[1];
    float* fp       = (float*)d_ws;
    float* gp       = fp + BB * NN;
    float* partials = gp + BB * NN;
    int*   bctr     = (int*)(partials + GRID_BLOCKS);
    int*   gctr     = bctr + BB * 32;
    float* out      = (float*)d_out;

    size_t zbytes = (size_t)(2 * BB * NN + GRID_BLOCKS) * sizeof(float)
                  + (size_t)(BB * 32 + 32) * sizeof(int);
    hipMemsetAsync(d_ws, 0, zbytes, stream);

    emd_persist<<<dim3(GRID_BLOCKS), dim3(TPB), 0, stream>>>(
        preds, gts, fp, gp, partials, bctr, gctr, out);
}

// Round 10
// 686.201 us; speedup vs baseline: 2.8035x; 1.3075x over previous
//
#include <hip/hip_runtime.h>

// Sinkhorn EMD, B=8, N=2048, eps=0.005, 50 iters.
// R10: shrink per-pass fixed overhead around the barrier.
//  - Row setup from LDS (sjall): p=(K/2)G, |p|^2=-K*w -> 1 ds_read_b128/row
//    instead of 3 global loads + norm, every pass.
//  - Sparse passes wave-autonomous: 16 waves x 4 rows x full range
//    (no pair merge, no extra syncthreads, 24 shuffles not 48).
//  - batch = blk&7 (XCD-locality heuristic, correctness-neutral).
// Validated invariants: IC-coherent atomics, no fences (R6); fully
// unrolled r-loops (R8); online LSE 0-5 + fixed-shift M=own prev log-sum,
// builds at {6,7}+24k, MARGIN=48, CAP=256 (R9, absmax 0.0).

#define BB 8
#define NN 2048
#define NPASS 100
#define ONLINE_PASSES 6
#define RPD 8                 // rows/wave, dense mapping (8 grp x 2 half)
#define RPS 4                 // rows/wave, sparse mapping (16 waves)
#define GRID_BLOCKS 256
#define BLOCKS_PER_BATCH 32
#define TPB 1024
#define CAP 256
#define MARGIN 48.0f

constexpr float EPSV = 0.005f;
constexpr float KS   = EPSV * 0.69314718055994531f; // eps*ln2
constexpr float INVK = 1.0f / KS;
constexpr float C1V  = -EPSV * 7.6246189861593985f; // eps*log(1/2048)
constexpr float KQ4  = KS * 0.25f;
constexpr float TWOI = 2.0f * INVK;
constexpr float HK   = KS * 0.5f;                   // p = HK * G

__device__ __forceinline__ float fexp2(float x) { return __builtin_amdgcn_exp2f(x); }
__device__ __forceinline__ float flog2(float x) { return __builtin_amdgcn_logf(x); }

__device__ __forceinline__ float cohLoad(const float* p) {
    return __hip_atomic_load(p, __ATOMIC_RELAXED, __HIP_MEMORY_SCOPE_AGENT);
}
__device__ __forceinline__ void cohStore(float* p, float v) {
    __hip_atomic_store(p, v, __ATOMIC_RELAXED, __HIP_MEMORY_SCOPE_AGENT);
}

__device__ __forceinline__ void barrier_sync(int* ctr, int target) {
    __syncthreads();     // all waves' sc1 stores drained (vmcnt0 before s_barrier)
    if (threadIdx.x == 0) {
        __hip_atomic_fetch_add(ctr, 1, __ATOMIC_RELAXED, __HIP_MEMORY_SCOPE_AGENT);
        while (__hip_atomic_load(ctr, __ATOMIC_RELAXED, __HIP_MEMORY_SCOPE_AGENT) < target) {
            __builtin_amdgcn_s_sleep(2);
        }
    }
    __syncthreads();
}

__global__ void __launch_bounds__(TPB, 4) emd_persist(
    const float* __restrict__ preds, const float* __restrict__ gts,
    float* __restrict__ fpot, float* __restrict__ gpot,
    float* __restrict__ partials, int* __restrict__ bctr, int* __restrict__ gctr,
    float* __restrict__ out)
{
    __shared__ float4 sjall[2 * NN];         // side0=gts, side1=preds
    __shared__ float  sa[NN];                // active-col potential / K
    __shared__ float  sPrevL[2][64];         // [side][row-in-block] last log-sum
    __shared__ float  smS[64][2];            // dense pair-merge s
    __shared__ float  smM[64][2];            // dense pair-merge m
    __shared__ float  wred[16];
    __shared__ unsigned short slist[2][64][CAP];
    __shared__ unsigned int   scnt[2][64];

    const int blk  = blockIdx.x;
    const int b    = blk & 7;                // batch = XCD-mate heuristic
    const int rb   = blk >> 3;               // 32 row-blocks per batch
    const int wave = threadIdx.x >> 6;
    const int lane = threadIdx.x & 63;
    const int grp  = wave & 7;               // dense: row group
    const int half = wave >> 3;              // dense: column half
    const int cb   = half << 10;

    const float* pb  = preds + (size_t)b * NN * 3;
    const float* gbp = gts   + (size_t)b * NN * 3;
    float* fb = fpot + (size_t)b * NN;
    float* gb = gpot + (size_t)b * NN;
    int*   bar = bctr + b * 32;

    // one-time staging: G = 2g/K, w = -|g|^2/K  (both sides)
    for (int t = threadIdx.x; t < NN; t += TPB) {
        float gx = gbp[3*t], gy = gbp[3*t+1], gz = gbp[3*t+2];
        float Gx = gx*TWOI, Gy = gy*TWOI, Gz = gz*TWOI;
        sjall[t] = make_float4(Gx, Gy, Gz, -KQ4*(Gx*Gx+Gy*Gy+Gz*Gz));
        float qx = pb[3*t], qy = pb[3*t+1], qz = pb[3*t+2];
        float Qx = qx*TWOI, Qy = qy*TWOI, Qz = qz*TWOI;
        sjall[NN+t] = make_float4(Qx, Qy, Qz, -KQ4*(Qx*Qx+Qy*Qy+Qz*Qz));
    }
    __syncthreads();   // sjall visible to all waves before row setup reads it

#pragma unroll 1
    for (int pass = 0; pass < NPASS; ++pass) {
        const int odd = pass & 1;
        const float* pin  = odd ? fb  : gb;
        float*       pout = odd ? gb  : fb;
        const int    sjo  = odd ? NN  : 0;   // cols side
        const int    rso  = odd ? 0   : NN;  // rows side
        const bool is_build  = (pass >= ONLINE_PASSES) &&
                               (((pass - ONLINE_PASSES) % 24) < 2);
        const bool is_sparse = (pass >= ONLINE_PASSES) && !is_build;

        // stage active potential column (IC-coherent)
        for (int t = threadIdx.x; t < NN; t += TPB)
            sa[t] = cohLoad(&pin[t]) * INVK;
        if (is_build && threadIdx.x < 64) scnt[odd][threadIdx.x] = 0;

        if (is_sparse) {
            // ---- wave-autonomous sparse pass: 4 rows, full range ----
            float qx[RPS], qy[RPS], qz[RPS], pc[RPS], M4[RPS], ss[RPS];
#pragma unroll
            for (int r = 0; r < RPS; ++r) {
                int rl = wave*RPS + r;
                float4 dr = sjall[rso + rb*64 + rl];
                qx[r] = HK*dr.x; qy[r] = HK*dr.y; qz[r] = HK*dr.z;
                pc[r] = C1V - KS*dr.w;           // C1 + |p|^2
                M4[r] = sPrevL[odd][rl];
                ss[r] = 0.f;
            }
            __syncthreads();                     // sa ready
#pragma unroll
            for (int r = 0; r < RPS; ++r) {
                const int rl = wave*RPS + r;
                const unsigned int cnt = scnt[odd][rl];
                float s1 = 0.f;
                if (cnt <= CAP) {
#pragma unroll 1
                    for (unsigned int k = lane; k < cnt; k += 64) {
                        int j = slist[odd][rl][k];
                        float4 d = sjall[sjo + j];
                        float aw = d.w + sa[j];
                        float x = fmaf(qx[r], d.x, fmaf(qy[r], d.y, fmaf(qz[r], d.z, aw)));
                        s1 += fexp2(fminf(x - M4[r], 100.f));
                    }
                } else {
#pragma unroll 1
                    for (int c = 0; c < 32; ++c) {
                        int j = c*64 + lane;
                        float4 d = sjall[sjo + j];
                        float aw = d.w + sa[j];
                        float x = fmaf(qx[r], d.x, fmaf(qy[r], d.y, fmaf(qz[r], d.z, aw)));
                        s1 += fexp2(fminf(x - M4[r], 100.f));
                    }
                }
                ss[r] = s1;
            }
#pragma unroll
            for (int r = 0; r < RPS; ++r) {
                float v = ss[r];
                for (int off = 1; off < 64; off <<= 1) v += __shfl_xor(v, off, 64);
                ss[r] = v;
            }
            if (lane == 0) {
#pragma unroll
                for (int r = 0; r < RPS; ++r) {
                    int rl = wave*RPS + r;
                    float L = M4[r] + flog2(fmaxf(ss[r], 1e-37f));
                    sPrevL[odd][rl] = L;
                    cohStore(&pout[rb*64 + rl], pc[r] - KS * L);
                }
            }
            barrier_sync(bar, BLOCKS_PER_BATCH * (pass + 1));
            continue;
        }

        // ---- dense mapping: 8 rows x column half ----
        float qx[RPD], qy[RPD], qz[RPD], pc[RPD], M[RPD], s[RPD];
#pragma unroll
        for (int r = 0; r < RPD; ++r) {
            int rl = grp*RPD + r;
            float4 dr = sjall[rso + rb*64 + rl];
            qx[r] = HK*dr.x; qy[r] = HK*dr.y; qz[r] = HK*dr.z;
            pc[r] = C1V - KS*dr.w;
            s[r]  = 0.f;
        }
        if (pass >= ONLINE_PASSES) {
#pragma unroll
            for (int r = 0; r < RPD; ++r)
                M[r] = sPrevL[odd][grp*RPD + r];
        }
        __syncthreads();                         // sa ready

        if (pass < ONLINE_PASSES) {
            float m[RPD];
#pragma unroll
            for (int r = 0; r < RPD; ++r) m[r] = -1e30f;
#pragma unroll 4
            for (int c = 0; c < 16; ++c) {
                float4 d = sjall[sjo + cb + c*64 + lane];
                float aw = d.w + sa[cb + c*64 + lane];
#pragma unroll
                for (int r = 0; r < RPD; ++r) {
                    float x  = fmaf(qx[r], d.x, fmaf(qy[r], d.y, fmaf(qz[r], d.z, aw)));
                    float mn = fmaxf(m[r], x);
                    s[r] = fmaf(s[r], fexp2(m[r]-mn), fexp2(x-mn));
                    m[r] = mn;
                }
            }
#pragma unroll
            for (int r = 0; r < RPD; ++r) {
                float mm = m[r], sv = s[r];
                for (int off = 1; off < 64; off <<= 1) {
                    float mo = __shfl_xor(mm, off, 64);
                    float so = __shfl_xor(sv, off, 64);
                    float mn = fmaxf(mm, mo);
                    sv = fmaf(sv, fexp2(mm-mn), so * fexp2(mo-mn));
                    mm = mn;
                }
                m[r] = mm; s[r] = sv;
            }
            if (lane == 0) {
#pragma unroll
                for (int r = 0; r < RPD; ++r) {
                    smM[grp*RPD + r][half] = m[r];
                    smS[grp*RPD + r][half] = s[r];
                }
            }
            __syncthreads();
            if (half == 1 && lane == 0) {
#pragma unroll
                for (int r = 0; r < RPD; ++r) {
                    float mo = smM[grp*RPD + r][0], so = smS[grp*RPD + r][0];
                    float mn = fmaxf(m[r], mo);
                    float st = fmaf(s[r], fexp2(m[r]-mn), so * fexp2(mo-mn));
                    float L  = mn + flog2(fmaxf(st, 1e-37f));
                    sPrevL[odd][grp*RPD + r] = L;
                    cohStore(&pout[rb*64 + grp*RPD + r], pc[r] - KS * L);
                }
            }
        } else {
            // build: dense fixed-shift + candidate compaction
#pragma unroll
            for (int r = 0; r < RPD; ++r) {
                const int rl = grp*RPD + r;
                const float thr = M[r] - MARGIN;
                float s1 = 0.f;
#pragma unroll 1
                for (int c = 0; c < 16; ++c) {
                    int j = cb + c*64 + lane;
                    float4 d = sjall[sjo + j];
                    float aw = d.w + sa[j];
                    float x = fmaf(qx[r], d.x, fmaf(qy[r], d.y, fmaf(qz[r], d.z, aw)));
                    s1 += fexp2(fminf(x - M[r], 100.f));
                    bool pred = (x >= thr);
                    unsigned long long mask = __ballot((int)pred);
                    int npop = __popcll(mask);
                    unsigned int base = 0;
                    if (lane == 0 && npop)
                        base = atomicAdd(&scnt[odd][rl], (unsigned)npop);
                    base = (unsigned)__shfl((int)base, 0, 64);
                    if (pred) {
                        unsigned int pos = base + __popcll(mask & ((1ull << lane) - 1ull));
                        if (pos < CAP) slist[odd][rl][pos] = (unsigned short)j;
                    }
                }
                s[r] = s1;
            }
#pragma unroll
            for (int r = 0; r < RPD; ++r) {
                float v = s[r];
                for (int off = 1; off < 64; off <<= 1) v += __shfl_xor(v, off, 64);
                s[r] = v;
            }
            if (lane == 0) {
#pragma unroll
                for (int r = 0; r < RPD; ++r) smS[grp*RPD + r][half] = s[r];
            }
            __syncthreads();
            if (half == 1 && lane == 0) {
#pragma unroll
                for (int r = 0; r < RPD; ++r) {
                    float st = s[r] + smS[grp*RPD + r][0];
                    float L  = M[r] + flog2(fmaxf(st, 1e-37f));
                    sPrevL[odd][grp*RPD + r] = L;
                    cohStore(&pout[rb*64 + grp*RPD + r], pc[r] - KS * L);
                }
            }
        }
        barrier_sync(bar, BLOCKS_PER_BATCH * (pass + 1));
    }

    // ---- dis: sum P*C, sparse mapping, f-side lists (side 0) ----
    for (int t = threadIdx.x; t < NN; t += TPB)
        sa[t] = cohLoad(&gb[t]) * INVK;

    float qx[RPS], qy[RPS], qz[RPS], pn4[RPS], bb2[RPS], acc[RPS];
#pragma unroll
    for (int r = 0; r < RPS; ++r) {
        int rl = wave*RPS + r;
        float4 dr = sjall[NN + rb*64 + rl];      // rows = preds
        qx[r] = HK*dr.x; qy[r] = HK*dr.y; qz[r] = HK*dr.z;
        pn4[r] = -KS*dr.w;
        bb2[r] = C1V * INVK - sPrevL[0][rl];
        acc[r] = 0.f;
    }
    __syncthreads();
#pragma unroll
    for (int r = 0; r < RPS; ++r) {
        const int rl = wave*RPS + r;
        const unsigned int cnt = scnt[0][rl];
        float aa = 0.f;
        if (cnt <= CAP) {
#pragma unroll 1
            for (unsigned int k = lane; k < cnt; k += 64) {
                int j = slist[0][rl][k];
                float4 d = sjall[j];
                float aw = d.w + sa[j];
                float dot = fmaf(qx[r], d.x, fmaf(qy[r], d.y, qz[r]*d.z));
                float y   = dot + aw + bb2[r];
                float e   = fexp2(fminf(y, 80.f));
                aa = fmaf(e, fmaf(-KS, dot, pn4[r] - KS*d.w), aa);
            }
        } else {
#pragma unroll 1
            for (int c = 0; c < 32; ++c) {
                int j = c*64 + lane;
                float4 d = sjall[j];
                float aw = d.w + sa[j];
                float dot = fmaf(qx[r], d.x, fmaf(qy[r], d.y, qz[r]*d.z));
                float y   = dot + aw + bb2[r];
                float e   = fexp2(fminf(y, 80.f));
                aa = fmaf(e, fmaf(-KS, dot, pn4[r] - KS*d.w), aa);
            }
        }
        acc[r] = aa;
    }
    float tot = acc[0] + acc[1] + acc[2] + acc[3];
    for (int off = 1; off < 64; off <<= 1) tot += __shfl_xor(tot, off, 64);
    if (lane == 0) wred[wave] = tot;
    __syncthreads();
    if (threadIdx.x == 0) {
        float v = 0.f;
        for (int w = 0; w < 16; ++w) v += wred[w];
        cohStore(&partials[blk], v);
    }

    barrier_sync(gctr, GRID_BLOCKS);

    if (blk == 0) {
        float v = (threadIdx.x < GRID_BLOCKS) ? cohLoad(&partials[threadIdx.x]) : 0.f;
        for (int off = 1; off < 64; off <<= 1) v += __shfl_xor(v, off, 64);
        if (lane == 0) wred[wave] = v;
        __syncthreads();
        if (threadIdx.x == 0) {
            float t2 = 0.f;
            for (int w = 0; w < 16; ++w) t2 += wred[w];
            out[0] = t2 * (1.0f / BB);
        }
    }
}

extern "C" void kernel_launch(void* const* d_in, const int* in_sizes, int n_in,
                              void* d_out, int out_size, void* d_ws, size_t ws_size,
                              hipStream_t stream) {
    const float* preds = (const float*)d_in[0];
    const float* gts   = (const float*)d_in[1];
    float* fp       = (float*)d_ws;
    float* gp       = fp + BB * NN;
    float* partials = gp + BB * NN;
    int*   bctr     = (int*)(partials + GRID_BLOCKS);
    int*   gctr     = bctr + BB * 32;
    float* out      = (float*)d_out;

    size_t zbytes = (size_t)(2 * BB * NN + GRID_BLOCKS) * sizeof(float)
                  + (size_t)(BB * 32 + 32) * sizeof(int);
    hipMemsetAsync(d_ws, 0, zbytes, stream);

    emd_persist<<<dim3(GRID_BLOCKS), dim3(TPB), 0, stream>>>(
        preds, gts, fp, gp, partials, bctr, gctr, out);
}